// Round 5
// baseline (381.466 us; speedup 1.0000x reference)
//
#include <hip/hip_runtime.h>

// Problem constants (fixed by the reference)
#define NN 8192
#define NE 262144

__device__ __forceinline__ float bf2f(unsigned short h) {
    return __uint_as_float(((unsigned int)h) << 16);
}

// Runtime float-dtype hedge: bf16-packed data has EVERY 16-bit half looking
// like a bf16 float of moderate exponent; genuine fp32 data has uniform
// mantissa bits in the low halves. Check low-half exponent field of 16 words.
__device__ __forceinline__ int detect_bf16(const void* p) {
    const unsigned int* w = (const unsigned int*)p;
    int all = 1;
    for (int i = 0; i < 16; ++i) {
        unsigned int el = (w[i] >> 7) & 0xFFu;  // low-half exponent field
        all &= (el >= 64u && el < 160u) ? 1 : 0;
    }
    return all;
}
__device__ __forceinline__ float loadf(const void* p, size_t i, int isbf) {
    return isbf ? bf2f(((const unsigned short*)p)[i]) : ((const float*)p)[i];
}

// ---------------------------------------------------------------------------
// Kernel 1: segment_sum of edge_attr by source node via global fp32 atomics.
// agg = fp32 [NN,4] scratch carved from the HEAD of the (fp32) adj output
// region; zeroed by hipMemsetAsync first; k_decode overwrites it afterwards.
// edge_index hedge: little-endian int64 values < 8192 have zero odd words.
// ---------------------------------------------------------------------------
__global__ __launch_bounds__(256) void k_edge_agg(
    const int* edge_index, const void* edge_attr, float* agg)
{
    const int e = blockIdx.x * 256 + threadIdx.x;
    if (e >= NE) return;
    const bool is64 =
        (edge_index[1] | edge_index[3] | edge_index[5] | edge_index[7] |
         edge_index[9] | edge_index[11] | edge_index[13] | edge_index[15]) == 0;
    const int r = is64 ? edge_index[2 * e] : edge_index[e];
    const int isbf = detect_bf16(edge_attr);
    float* dst = agg + (size_t)r * 4;
    atomicAdd(dst + 0, loadf(edge_attr, (size_t)e * 4 + 0, isbf));
    atomicAdd(dst + 1, loadf(edge_attr, (size_t)e * 4 + 1, isbf));
    atomicAdd(dst + 2, loadf(edge_attr, (size_t)e * 4 + 2, isbf));
    atomicAdd(dst + 3, loadf(edge_attr, (size_t)e * 4 + 3, isbf));
}

// ---------------------------------------------------------------------------
// Kernel 2: node MLP chain (15->4->4->2) in fp32, one thread per node.
// Writes fp32 emb to the output-1 region (d_out + NN*NN fp32 elements).
// ---------------------------------------------------------------------------
__global__ __launch_bounds__(256) void k_node_mlp(
    const float* agg, const void* node_feats,
    const void* W1, const void* b1, const void* W2, const void* b2,
    const void* We, const void* be,
    float* emb)                 // fp32 [NN,2] at d_out tail
{
    const int n = blockIdx.x * 256 + threadIdx.x;
    if (n >= NN) return;
    const int isbf = detect_bf16(node_feats);  // same policy for all floats

    float in[15];
    for (int k = 0; k < 11; ++k) in[k] = loadf(node_feats, (size_t)n * 11 + k, isbf);
    for (int c = 0; c < 4; ++c)  in[11 + c] = agg[(size_t)n * 4 + c];

    float h[4];
    for (int j = 0; j < 4; ++j) {
        float acc = loadf(b1, j, isbf);
        for (int k = 0; k < 15; ++k) acc += in[k] * loadf(W1, k * 4 + j, isbf);
        h[j] = acc;
    }
    float o[4];
    for (int j = 0; j < 4; ++j) {
        float acc = loadf(b2, j, isbf);
        for (int k = 0; k < 4; ++k) acc += h[k] * loadf(W2, k * 4 + j, isbf);
        o[j] = acc;
    }
    float e0 = loadf(be, 0, isbf), e1 = loadf(be, 1, isbf);
    for (int k = 0; k < 4; ++k) {
        e0 += o[k] * loadf(We, k * 2 + 0, isbf);
        e1 += o[k] * loadf(We, k * 2 + 1, isbf);
    }
    emb[(size_t)n * 2 + 0] = e0;
    emb[(size_t)n * 2 + 1] = e1;
}

// ---------------------------------------------------------------------------
// Kernel 3: decode — adj[i][j] = sigmoid(10*||emb_i - emb_j||^2 - 1), diag 0.
// fp32 output. 256 threads x 4 consecutive cols (float4 store), 64 rows/block.
// Grid = 8 col-blocks x 128 row-blocks = 1024 blocks; coverage trivially total.
// ---------------------------------------------------------------------------
__global__ __launch_bounds__(256) void k_decode(
    const float* emb, float* adj)
{
    __shared__ float xi[64], yi[64];
    const int cb = blockIdx.x & 7;       // 8 col blocks of 1024
    const int rb = blockIdx.x >> 3;      // 128 row blocks of 64
    const int r0 = rb * 64;
    const int t  = threadIdx.x;
    const int jbase = cb * 1024 + t * 4;

    float xj[4], yj[4];
    for (int k = 0; k < 4; ++k) {
        xj[k] = emb[(size_t)(jbase + k) * 2 + 0];
        yj[k] = emb[(size_t)(jbase + k) * 2 + 1];
    }
    if (t < 64) {
        xi[t] = emb[(size_t)(r0 + t) * 2 + 0];
        yi[t] = emb[(size_t)(r0 + t) * 2 + 1];
    }
    __syncthreads();

    const float C1  = 1.4426950408889634f;   // log2(e)
    const float C10 = 14.426950408889634f;   // 10*log2(e)

    for (int r = 0; r < 64; ++r) {
        const int row = r0 + r;
        const float x = xi[r], y = yi[r];
        float4 v;
        float s[4];
        for (int k = 0; k < 4; ++k) {
            float dx = x - xj[k];
            float dy = y - yj[k];
            float d  = fmaf(dx, dx, dy * dy);
            // sigmoid(10d-1) = 1 / (1 + exp(1-10d)); exp via exp2
            float ex = exp2f(C1 - C10 * d);
            float sv = 1.0f / (1.0f + ex);
            if (jbase + k == row) sv = 0.0f;
            s[k] = sv;
        }
        v.x = s[0]; v.y = s[1]; v.z = s[2]; v.w = s[3];
        *(float4*)(adj + (size_t)row * NN + jbase) = v;
    }
}

// ---------------------------------------------------------------------------
extern "C" void kernel_launch(void* const* d_in, const int* in_sizes, int n_in,
                              void* d_out, int out_size, void* d_ws, size_t ws_size,
                              hipStream_t stream)
{
    const void* node_feats = d_in[0];
    const int*  edge_index = (const int*)d_in[1];
    const void* edge_attr  = d_in[2];
    const void* W1 = d_in[3];
    const void* b1 = d_in[4];
    const void* W2 = d_in[5];
    const void* b2 = d_in[6];
    const void* We = d_in[7];
    const void* be = d_in[8];

    float* adj = (float*)d_out;                     // fp32 [NN*NN]
    float* emb = adj + (size_t)NN * NN;             // fp32 [NN*2] (output 1)
    float* agg = adj;                               // fp32 [NN*4] scratch (head,
                                                    // overwritten by k_decode)

    hipMemsetAsync(agg, 0, (size_t)NN * 4 * sizeof(float), stream);

    hipLaunchKernelGGL(k_edge_agg, dim3(NE / 256), dim3(256), 0, stream,
                       edge_index, edge_attr, agg);
    hipLaunchKernelGGL(k_node_mlp, dim3(NN / 256), dim3(256), 0, stream,
                       agg, node_feats, W1, b1, W2, b2, We, be, emb);
    hipLaunchKernelGGL(k_decode, dim3(1024), dim3(256), 0, stream, emb, adj);
}